// Round 4
// baseline (672.648 us; speedup 1.0000x reference)
//
#include <hip/hip_runtime.h>

// S = 256. Out[b][D][q] = sum_k softmax_k(QK^T/16)[b,q,k]*keep[b,q,k]*v[b,k,D]
// qk_bias is a per-(b,q) additive constant before softmax -> softmax-invariant -> skipped.
// d_ws holds vT[b][D][k] as bf16: 256^3 * 2 = 33,554,432 bytes.
//
// Round-7: barrier-free streaming rewrite. Rounds 4-6 proved the kernels are
// neither pipe-bound nor fixed by sync finesse (occupancy 2x'd: neutral;
// vmcnt-preserving barriers: neutral; all pipes <30% busy). The bottleneck
// class is the LDS-staging + block-rendezvous structure itself (16 MFMA per
// barrier per wave is 4x below the granularity where phase pipelining pays).
// Observation: the staged K/vT/V fragments are IDENTICAL across the 4 waves
// of a block (no dependence on w) -> stream them directly from global
// (L1/L2 serve the re-reads) and make every wave fully independent:
//  * attn: ZERO s_barrier. K fragments f32->cvt inline from global; vT
//    fragments (bf16, 16B aligned) from global. LDS only holds the per-wave
//    PRIVATE P-transpose (lgkmcnt + sched_barrier, no s_barrier).
//  * vproj: one barrier total (one-time W^T stage); V streamed from global;
//    epilogue bounce made wave-private (no barrier).
//  * __launch_bounds__(256,3): VGPR cap ~170 vs ~150 est. live set.

#define SDIM 256
#define LDSP 264  // padded LDS row stride (elements); 264*2=528B, 16B-aligned

typedef __bf16 bf16_t;
typedef __bf16 bf16x8 __attribute__((ext_vector_type(8)));
typedef __bf16 bf16x4 __attribute__((ext_vector_type(4)));
typedef float f32x4 __attribute__((ext_vector_type(4)));

__device__ inline bf16x8 cvt8(float4 a, float4 b) {
  bf16x8 r;
  r[0] = (bf16_t)a.x; r[1] = (bf16_t)a.y; r[2] = (bf16_t)a.z; r[3] = (bf16_t)a.w;
  r[4] = (bf16_t)b.x; r[5] = (bf16_t)b.y; r[6] = (bf16_t)b.z; r[7] = (bf16_t)b.w;
  return r;
}
__device__ inline bf16x4 cvt4(float4 a) {
  bf16x4 r;
  r[0] = (bf16_t)a.x; r[1] = (bf16_t)a.y; r[2] = (bf16_t)a.z; r[3] = (bf16_t)a.w;
  return r;
}

// Wave-private LDS write->read fence: drain DS queue, and stop the scheduler
// from hoisting the following ds_reads above it (rule: inline-asm lgkmcnt
// needs a sched_barrier to be authoritative).
__device__ inline void lds_fence() {
  asm volatile("s_waitcnt lgkmcnt(0)" ::: "memory");
  __builtin_amdgcn_sched_barrier(0);
}

// ---------------------------------------------------------------------------
// Kernel 1: vT[b][D][k] = sum_d W[b][d][D]*value[b][k][d] + v_bias[k][D], bf16
// grid = 1024 (XCD-swizzled (b, Dblk)); block = 256 (4 independent waves).
// One barrier total (W^T stage); V fragments streamed from global.
// ---------------------------------------------------------------------------
__global__ __launch_bounds__(256, 3) void vproj_kernel(
    const float* __restrict__ value, const float* __restrict__ v_weight,
    const float* __restrict__ v_bias, bf16_t* __restrict__ vT)
{
  __shared__ bf16_t SH[64 * LDSP];

  // XCD swizzle: all 4 Dblks of a given b share xcd = b & 7.
  const int pidx = blockIdx.x;
  const int xcd  = pidx & 7;
  const int jj   = pidx >> 3;
  const int Dblk = jj & 3;
  const int b    = xcd + ((jj >> 2) << 3);
  const int Dbase = Dblk * 64;

  const int t    = threadIdx.x;
  const int w    = t >> 6;
  const int lane = t & 63;
  const int lid  = lane & 15;
  const int quad = lane >> 4;

  const float* Wb = v_weight + (size_t)b * (SDIM * SDIM);
  const float* Vb = value    + (size_t)b * (SDIM * SDIM);

  // Bias preload (scattered, hidden behind the GEMM).
  bf16x4 biasr[16];
  {
    const float* bp = v_bias + Dbase + w * 16 + quad * 4;
    #pragma unroll
    for (int n = 0; n < 16; ++n)
      biasr[n] = cvt4(*(const float4*)(bp + (n * 16 + lid) * SDIM));
  }

  // Stage W^T tile (bf16) into SH once; cache A-fragments in registers.
  // (cross-wave: staging layout is row=D-local, so one barrier needed.)
  {
    const int c4 = (t & 15) * 4;
    const int r0 = t >> 4;
    #pragma unroll
    for (int p = 0; p < 16; ++p) {
      const int r = p * 16 + r0;
      float4 f = *(const float4*)(Wb + r * SDIM + Dbase + c4);
      SH[(c4 + 0) * LDSP + r] = (bf16_t)f.x;
      SH[(c4 + 1) * LDSP + r] = (bf16_t)f.y;
      SH[(c4 + 2) * LDSP + r] = (bf16_t)f.z;
      SH[(c4 + 3) * LDSP + r] = (bf16_t)f.w;
    }
  }
  __syncthreads();  // the only block-wide barrier in this kernel
  bf16x8 af[8];
  #pragma unroll
  for (int d = 0; d < 8; ++d)
    af[d] = *(const bf16x8*)(&SH[(w * 16 + lid) * LDSP + d * 32 + quad * 8]);

  f32x4 acc[16];
  #pragma unroll
  for (int n = 0; n < 16; ++n) acc[n] = (f32x4){0.f, 0.f, 0.f, 0.f};

  // Stream V fragments directly from global (identical addresses across the
  // 4 waves -> L1/L2 amortize). Fully unrolled; compiler pipelines loads.
  #pragma unroll
  for (int s = 0; s < 8; ++s) {
    #pragma unroll
    for (int n4 = 0; n4 < 2; ++n4) {
      const int n = s * 2 + n4;
      #pragma unroll
      for (int d = 0; d < 8; ++d) {
        const float* p = Vb + (s * 32 + n4 * 16 + lid) * SDIM + d * 32 + quad * 8;
        float4 a = *(const float4*)(p);
        float4 c = *(const float4*)(p + 4);
        acc[n] = __builtin_amdgcn_mfma_f32_16x16x32_bf16(af[d], cvt8(a, c), acc[n], 0, 0, 0);
      }
    }
  }

  // Epilogue: add bias, bounce via SH (WAVE-PRIVATE rows -> no barrier),
  // then full-line coalesced stores of this wave's 16 D-rows.
  #pragma unroll
  for (int n = 0; n < 16; ++n) {
    const int k = n * 16 + lid;
    #pragma unroll
    for (int j = 0; j < 4; ++j) {
      const int Dloc = w * 16 + quad * 4 + j;
      SH[Dloc * LDSP + k] = (bf16_t)(acc[n][j] + (float)biasr[n][j]);
    }
  }
  lds_fence();
  bf16_t* outb = vT + (size_t)b * (SDIM * SDIM) + (size_t)Dbase * SDIM;
  #pragma unroll
  for (int p = 0; p < 8; ++p) {
    const int r = w * 16 + p * 2 + (lane >> 5);   // within this wave's rows
    const int c = (lane & 31) * 8;
    bf16x8 h = *(const bf16x8*)(&SH[r * LDSP + c]);
    *(bf16x8*)(outb + r * SDIM + c) = h;
  }
}

// ---------------------------------------------------------------------------
// Kernel 2: fused attention. grid = 1024 (XCD-swizzled (b, qt)); block = 256.
// ZERO block-wide barriers: 4 independent waves, 16 q-rows each.
// ---------------------------------------------------------------------------
__global__ __launch_bounds__(256, 3) void attn_kernel(
    const float* __restrict__ query, const float* __restrict__ key,
    const float* __restrict__ drop_u, const bf16_t* __restrict__ vT,
    float* __restrict__ out)
{
  __shared__ bf16_t PT[64 * LDSP];  // per-wave-private P transpose (16 rows/wave)

  const int pidx = blockIdx.x;
  const int xcd  = pidx & 7;
  const int jj   = pidx >> 3;
  const int qt   = jj & 3;
  const int b    = xcd + ((jj >> 2) << 3);

  const int t    = threadIdx.x;
  const int w    = t >> 6;
  const int lane = t & 63;
  const int lid  = lane & 15;
  const int quad = lane >> 4;
  const int q0   = qt * 64 + w * 16;

  const float* Qb = query + (size_t)b * (SDIM * SDIM);
  const float* Kb = key   + (size_t)b * (SDIM * SDIM);

  // Q fragments (A-layout: row = q0+lid, k = d*32 + quad*8 + j).
  bf16x8 qf[8];
  #pragma unroll
  for (int d = 0; d < 8; ++d) {
    const float* p = Qb + (q0 + lid) * SDIM + d * 32 + quad * 8;
    float4 a = *(const float4*)(p);
    float4 c = *(const float4*)(p + 4);
    qf[d] = cvt8(a, c);
  }

  f32x4 sacc[16];
  #pragma unroll
  for (int n = 0; n < 16; ++n) sacc[n] = (f32x4){0.f, 0.f, 0.f, 0.f};

  // Phase A: S = QK^T, K fragments streamed directly from global (f32 ->
  // inline cvt). Identical addresses across the 4 waves -> L1/L2 amortize.
  #pragma unroll
  for (int s = 0; s < 8; ++s) {
    #pragma unroll
    for (int n4 = 0; n4 < 2; ++n4) {
      const int n = s * 2 + n4;
      #pragma unroll
      for (int d = 0; d < 8; ++d) {
        const float* p = Kb + (s * 32 + n4 * 16 + lid) * SDIM + d * 32 + quad * 8;
        float4 a = *(const float4*)(p);
        float4 c = *(const float4*)(p + 4);
        sacc[n] = __builtin_amdgcn_mfma_f32_16x16x32_bf16(qf[d], cvt8(a, c), sacc[n], 0, 0, 0);
      }
    }
  }

  // Softmax per q-row (C-layout: q = quad*4+j, key = n*16+lid). Register-only.
  #pragma unroll
  for (int j = 0; j < 4; ++j) {
    float mx = sacc[0][j];
    #pragma unroll
    for (int n = 1; n < 16; ++n) mx = fmaxf(mx, sacc[n][j]);
    #pragma unroll
    for (int off = 8; off >= 1; off >>= 1) mx = fmaxf(mx, __shfl_xor(mx, off, 64));
    float sum = 0.f;
    #pragma unroll
    for (int n = 0; n < 16; ++n) {
      float e = __expf((sacc[n][j] - mx) * 0.0625f);
      sacc[n][j] = e;
      sum += e;
    }
    #pragma unroll
    for (int off = 8; off >= 1; off >>= 1) sum += __shfl_xor(sum, off, 64);
    float inv = 1.0f / sum;
    #pragma unroll
    for (int n = 0; n < 16; ++n) sacc[n][j] *= inv;
  }

  // P transpose through WAVE-PRIVATE LDS rows (w*16 .. w*16+15): C-layout in,
  // B-layout out. No s_barrier -- only a wave-level DS fence.
  #pragma unroll
  for (int n = 0; n < 16; ++n) {
    #pragma unroll
    for (int j = 0; j < 4; ++j)
      PT[(w * 16 + quad * 4 + j) * LDSP + n * 16 + lid] = (bf16_t)sacc[n][j];
  }
  lds_fence();

  bf16x8 pf[8];
  #pragma unroll
  for (int k0 = 0; k0 < 8; ++k0)
    pf[k0] = *(const bf16x8*)(&PT[(w * 16 + lid) * LDSP + k0 * 32 + quad * 8]);

  // Dropout in-register in the pf layout (q-row = q0+lid, k = k0*32+quad*8+j).
  {
    const float* Ub = drop_u + (size_t)b * (SDIM * SDIM) + (size_t)(q0 + lid) * SDIM + quad * 8;
    const float rs = 1.0f / 0.9f;
    #pragma unroll
    for (int k0 = 0; k0 < 8; ++k0) {
      float4 u0 = *(const float4*)(Ub + k0 * 32);
      float4 u1 = *(const float4*)(Ub + k0 * 32 + 4);
      pf[k0][0] = (u0.x >= 0.1f) ? (bf16_t)((float)pf[k0][0] * rs) : (bf16_t)0.f;
      pf[k0][1] = (u0.y >= 0.1f) ? (bf16_t)((float)pf[k0][1] * rs) : (bf16_t)0.f;
      pf[k0][2] = (u0.z >= 0.1f) ? (bf16_t)((float)pf[k0][2] * rs) : (bf16_t)0.f;
      pf[k0][3] = (u0.w >= 0.1f) ? (bf16_t)((float)pf[k0][3] * rs) : (bf16_t)0.f;
      pf[k0][4] = (u1.x >= 0.1f) ? (bf16_t)((float)pf[k0][4] * rs) : (bf16_t)0.f;
      pf[k0][5] = (u1.y >= 0.1f) ? (bf16_t)((float)pf[k0][5] * rs) : (bf16_t)0.f;
      pf[k0][6] = (u1.z >= 0.1f) ? (bf16_t)((float)pf[k0][6] * rs) : (bf16_t)0.f;
      pf[k0][7] = (u1.w >= 0.1f) ? (bf16_t)((float)pf[k0][7] * rs) : (bf16_t)0.f;
    }
  }

  // Phase B: out^T[D][q] = vT * P^T, vT fragments (bf16, 16B-aligned) streamed
  // directly from global; per-slab streaming stores.
  const bf16_t* vTb = vT + (size_t)b * (SDIM * SDIM);
  float* outbp = out + (size_t)b * (SDIM * SDIM);

  #pragma unroll
  for (int s = 0; s < 8; ++s) {
    f32x4 o0 = (f32x4){0.f, 0.f, 0.f, 0.f};
    f32x4 o1 = (f32x4){0.f, 0.f, 0.f, 0.f};
    #pragma unroll
    for (int k0 = 0; k0 < 8; ++k0) {
      bf16x8 a0 = *(const bf16x8*)(vTb + (s * 32 + lid) * SDIM + k0 * 32 + quad * 8);
      bf16x8 a1 = *(const bf16x8*)(vTb + (s * 32 + 16 + lid) * SDIM + k0 * 32 + quad * 8);
      o0 = __builtin_amdgcn_mfma_f32_16x16x32_bf16(a0, pf[k0], o0, 0, 0, 0);
      o1 = __builtin_amdgcn_mfma_f32_16x16x32_bf16(a1, pf[k0], o1, 0, 0, 0);
    }
    #pragma unroll
    for (int j = 0; j < 4; ++j) {
      outbp[(s * 32 + quad * 4 + j) * SDIM + q0 + lid] = o0[j];
      outbp[(s * 32 + 16 + quad * 4 + j) * SDIM + q0 + lid] = o1[j];
    }
  }
}

extern "C" void kernel_launch(void* const* d_in, const int* in_sizes, int n_in,
                              void* d_out, int out_size, void* d_ws, size_t ws_size,
                              hipStream_t stream) {
  (void)in_sizes; (void)n_in; (void)out_size; (void)ws_size;
  const float* query    = (const float*)d_in[0];
  const float* key      = (const float*)d_in[1];
  const float* value    = (const float*)d_in[2];
  const float* drop_u   = (const float*)d_in[3];
  // d_in[4] = qk_bias: softmax-invariant -> skipped.
  const float* v_weight = (const float*)d_in[5];
  const float* v_bias   = (const float*)d_in[6];
  float* out = (float*)d_out;
  bf16_t* vT = (bf16_t*)d_ws;  // 33,554,432 bytes of workspace

  vproj_kernel<<<dim3(1024), dim3(256), 0, stream>>>(value, v_weight, v_bias, vT);
  attn_kernel<<<dim3(1024), dim3(256), 0, stream>>>(query, key, drop_u, vT, out);
}